// Round 1
// baseline (794.087 us; speedup 1.0000x reference)
//
#include <hip/hip_runtime.h>
#include <stdint.h>
#include <math.h>

// ---------------------------------------------------------------------------
// HNetv1: corr-volume (l2norm + batched 144x128x144 GEMM) -> MLP 20736->5184
// ->1296->324->8, relu/relu/tanh, concat ones -> [64,3,3].
// Dominant cost: reading W1 (430 MB fp32) once -> HBM-bound ~68us floor.
// Strategy: bf16 MFMA 16x16x32 with on-the-fly fp32->bf16 weight conversion,
// split-K + fp32 atomics for grid-wide BW saturation.
// ---------------------------------------------------------------------------

typedef short short8 __attribute__((ext_vector_type(8)));
typedef float f32x4 __attribute__((ext_vector_type(4)));
typedef unsigned int uint2v __attribute__((ext_vector_type(2)));

__device__ __forceinline__ unsigned bf16u(float x) {
    return (__float_as_uint(x) + 0x8000u) >> 16;   // round-half-up to bf16
}
__device__ __forceinline__ unsigned packbf(float a, float b) {
    return ((__float_as_uint(a) + 0x8000u) >> 16) |
           ((__float_as_uint(b) + 0x8000u) & 0xFFFF0000u);
}
__device__ __forceinline__ float bf2f(unsigned short u) {
    return __uint_as_float(((unsigned)u) << 16);
}

// ---------------------------------------------------------------------------
// Kernel 1: per (n, which) block: l2-normalize over c and write transposed
// bf16 [n][ij][c] so MFMA fragments become contiguous 16B runs along c.
// ---------------------------------------------------------------------------
__global__ __launch_bounds__(256) void knorm(const float* __restrict__ x1,
                                             const float* __restrict__ x2,
                                             unsigned short* __restrict__ x1nt,
                                             unsigned short* __restrict__ x2nt) {
    __shared__ unsigned short s[128 * 148];   // [c][ij], pad 144->148
    __shared__ float rn[144];
    int b = blockIdx.x;              // 0..127
    int n = b >> 1;
    const float* src = (b & 1) ? x2 + n * 18432 : x1 + n * 18432;
    unsigned short* dst = (b & 1) ? x2nt + n * 18432 : x1nt + n * 18432;
    int t = threadIdx.x;
    for (int i = 0; i < 72; ++i) {               // coalesced global read
        int g = t + 256 * i;
        int c = g / 144, ij = g - c * 144;
        s[c * 148 + ij] = (unsigned short)bf16u(src[g]);
    }
    __syncthreads();
    if (t < 144) {                                // per-(i,j) channel norm
        float acc = 0.f;
        for (int c = 0; c < 128; ++c) {
            float v = bf2f(s[c * 148 + t]);
            acc += v * v;
        }
        rn[t] = 1.0f / sqrtf(acc);
    }
    __syncthreads();
    for (int i = 0; i < 72; ++i) {               // transposed coalesced write
        int o = t + 256 * i;
        int ij = o >> 7, c = o & 127;
        float v = bf2f(s[c * 148 + ij]);
        dst[o] = (unsigned short)bf16u(v * rn[ij]);
    }
}

// ---------------------------------------------------------------------------
// Kernel 2: corr[n][k][ij] = sum_c x2nt[n][k][c] * x1nt[n][ij][c]
// One block per n; 81 16x16 tiles over (k,ij); K=c=128 -> 4 MFMA steps.
// A-frag layout: A[m=lane&15][k=(lane>>4)*8+j]; C/D: col=lane&15,
// row=(lane>>4)*4+reg  [measured m89/m120].
// ---------------------------------------------------------------------------
__global__ __launch_bounds__(256) void kcorr(const unsigned short* __restrict__ x1nt,
                                             const unsigned short* __restrict__ x2nt,
                                             unsigned short* __restrict__ Abuf) {
    int n = blockIdx.x;
    int lane = threadIdx.x & 63;
    int w = threadIdx.x >> 6;
    int col = lane & 15, quad = lane >> 4;
    const unsigned short* p1 = x1nt + n * 18432;
    const unsigned short* p2 = x2nt + n * 18432;
    unsigned short* out = Abuf + n * 20736;
    for (int tt = w; tt < 81; tt += 4) {
        int m0 = (tt / 9) * 16, n0 = (tt % 9) * 16;
        f32x4 acc = {0.f, 0.f, 0.f, 0.f};
        const short8* a0 = (const short8*)(p2 + (m0 + col) * 128 + quad * 8);
        const short8* b0 = (const short8*)(p1 + (n0 + col) * 128 + quad * 8);
#pragma unroll
        for (int ks = 0; ks < 4; ++ks) {
            short8 a = a0[ks * 4];      // +32 bf16 along c
            short8 bv = b0[ks * 4];
            acc = __builtin_amdgcn_mfma_f32_16x16x32_bf16(a, bv, acc, 0, 0, 0);
        }
#pragma unroll
        for (int r = 0; r < 4; ++r) {
            int row = m0 + quad * 4 + r;
            out[row * 144 + n0 + col] = (unsigned short)bf16u(acc[r]);
        }
    }
}

// ---------------------------------------------------------------------------
// Split-K GEMM: Cf[64][N] += A[64][KTOT](bf16) @ W[KTOT][N](fp32->bf16 otf)
// Block: 256 thr = 4 waves; wave w owns cols [bx*64+w*16, +16), all 64 rows
// (4 MFMA accumulators). blockIdx.y selects K-chunk. fp32 atomics epilogue.
// ---------------------------------------------------------------------------
template <int N, int KTOT, int KCHUNK>
__global__ __launch_bounds__(256) void kgemm(const unsigned short* __restrict__ A,
                                             const float* __restrict__ W,
                                             float* __restrict__ Cf) {
    int lane = threadIdx.x & 63;
    int w = threadIdx.x >> 6;
    int col = lane & 15, quad = lane >> 4;
    int c0 = blockIdx.x * 64 + w * 16;     // this wave's column base
    if (c0 >= N) return;                    // tail block (gemm2); no barriers used
    int kc = blockIdx.y * KCHUNK;
    const unsigned short* Ap = A + kc + quad * 8;
    const float* Wp = W + (size_t)(kc + quad * 8) * N + c0 + col;
    f32x4 acc0 = {0, 0, 0, 0}, acc1 = {0, 0, 0, 0}, acc2 = {0, 0, 0, 0}, acc3 = {0, 0, 0, 0};
#pragma unroll 2
    for (int ks = 0; ks < KCHUNK / 32; ++ks) {
        int kk = ks * 32;
        short8 a0 = *(const short8*)(Ap + (0 * 16 + col) * KTOT + kk);
        short8 a1 = *(const short8*)(Ap + (1 * 16 + col) * KTOT + kk);
        short8 a2 = *(const short8*)(Ap + (2 * 16 + col) * KTOT + kk);
        short8 a3 = *(const short8*)(Ap + (3 * 16 + col) * KTOT + kk);
        const float* wp = Wp + (size_t)kk * N;
        float b0 = __builtin_nontemporal_load(wp + 0 * (size_t)N);
        float b1 = __builtin_nontemporal_load(wp + 1 * (size_t)N);
        float b2 = __builtin_nontemporal_load(wp + 2 * (size_t)N);
        float b3 = __builtin_nontemporal_load(wp + 3 * (size_t)N);
        float b4 = __builtin_nontemporal_load(wp + 4 * (size_t)N);
        float b5 = __builtin_nontemporal_load(wp + 5 * (size_t)N);
        float b6 = __builtin_nontemporal_load(wp + 6 * (size_t)N);
        float b7 = __builtin_nontemporal_load(wp + 7 * (size_t)N);
        union { unsigned u[4]; short8 s; } bu;
        bu.u[0] = packbf(b0, b1);
        bu.u[1] = packbf(b2, b3);
        bu.u[2] = packbf(b4, b5);
        bu.u[3] = packbf(b6, b7);
        acc0 = __builtin_amdgcn_mfma_f32_16x16x32_bf16(a0, bu.s, acc0, 0, 0, 0);
        acc1 = __builtin_amdgcn_mfma_f32_16x16x32_bf16(a1, bu.s, acc1, 0, 0, 0);
        acc2 = __builtin_amdgcn_mfma_f32_16x16x32_bf16(a2, bu.s, acc2, 0, 0, 0);
        acc3 = __builtin_amdgcn_mfma_f32_16x16x32_bf16(a3, bu.s, acc3, 0, 0, 0);
    }
#pragma unroll
    for (int r = 0; r < 4; ++r) {
        int row0 = quad * 4 + r;
        atomicAdd(&Cf[(0 * 16 + row0) * N + c0 + col], acc0[r]);
        atomicAdd(&Cf[(1 * 16 + row0) * N + c0 + col], acc1[r]);
        atomicAdd(&Cf[(2 * 16 + row0) * N + c0 + col], acc2[r]);
        atomicAdd(&Cf[(3 * 16 + row0) * N + c0 + col], acc3[r]);
    }
}

// ---------------------------------------------------------------------------
// Epilogue: Cb = bf16(relu(Cf + bias[col])), vectorized x4.
// ---------------------------------------------------------------------------
template <int N>
__global__ __launch_bounds__(256) void kep(const float* __restrict__ Cf,
                                           const float* __restrict__ bias,
                                           unsigned short* __restrict__ Cb) {
    int idx = (blockIdx.x * 256 + threadIdx.x) * 4;
    int col = idx % N;
    f32x4 v = *(const f32x4*)(Cf + idx);
    f32x4 bb = *(const f32x4*)(bias + col);
    float r0 = fmaxf(v[0] + bb[0], 0.f);
    float r1 = fmaxf(v[1] + bb[1], 0.f);
    float r2 = fmaxf(v[2] + bb[2], 0.f);
    float r3 = fmaxf(v[3] + bb[3], 0.f);
    uint2v p = {packbf(r0, r1), packbf(r2, r3)};
    *(uint2v*)(Cb + idx) = p;
}

// ---------------------------------------------------------------------------
// GEMM3: C3f[n][col] += sum_k C2b[n][k]*W3[k][col], k-split by 4 (atomics).
// C2b row slice staged in LDS (broadcast reads), W3 reads coalesced.
// ---------------------------------------------------------------------------
__global__ __launch_bounds__(384) void kgemm3(const unsigned short* __restrict__ C2b,
                                              const float* __restrict__ W3,
                                              float* __restrict__ C3f) {
    __shared__ float as[324];
    int n = blockIdx.x, sl = blockIdx.y;
    int t = threadIdx.x;
    if (t < 324) as[t] = bf2f(C2b[n * 1296 + sl * 324 + t]);
    __syncthreads();
    if (t < 324) {
        float acc = 0.f;
        const float* wp = W3 + sl * 324 * 324 + t;
#pragma unroll 4
        for (int k = 0; k < 324; ++k) acc += as[k] * wp[k * 324];
        atomicAdd(&C3f[n * 324 + t], acc);
    }
}

// ---------------------------------------------------------------------------
// Epilogue3 + GEMM4 fused: t3 = tanh(C3f + b3) (LDS), H = t3 @ W4 + b4,
// out[n] = [H(8), 1] -> 9 floats.
// ---------------------------------------------------------------------------
__global__ __launch_bounds__(384) void kep3g4(const float* __restrict__ C3f,
                                              const float* __restrict__ b3,
                                              const float* __restrict__ W4,
                                              const float* __restrict__ b4,
                                              float* __restrict__ out) {
    __shared__ float t3[324];
    int n = blockIdx.x, t = threadIdx.x;
    if (t < 324) t3[t] = tanhf(C3f[n * 324 + t] + b3[t]);
    __syncthreads();
    if (t < 8) {
        float acc = b4[t];
        for (int k = 0; k < 324; ++k) acc += t3[k] * W4[k * 8 + t];
        out[n * 9 + t] = acc;
    } else if (t == 8) {
        out[n * 9 + 8] = 1.0f;
    }
}

// ---------------------------------------------------------------------------
// Workspace layout (bytes, all 256-aligned):
//   x1nt  @ 0         2359296   bf16 [64][144][128]
//   x2nt  @ 2359296   2359296   bf16 [64][144][128]
//   Abuf  @ 4718592   2654208   bf16 [64][20736]
//   C1f   @ 7372800   1327104   f32  [64][5184]   \
//   C2f   @ 8699904    331776   f32  [64][1296]    } one memset (1741824 B)
//   C3f   @ 9031680     82944   f32  [64][324]    /
//   C1b   @ 9114624    663552   bf16 [64][5184]
//   C2b   @ 9778176    165888   bf16 [64][1296]
// total ~9.95 MB
// ---------------------------------------------------------------------------
extern "C" void kernel_launch(void* const* d_in, const int* in_sizes, int n_in,
                              void* d_out, int out_size, void* d_ws, size_t ws_size,
                              hipStream_t stream) {
    const float* x1 = (const float*)d_in[0];
    const float* x2 = (const float*)d_in[1];
    const float* w1 = (const float*)d_in[2];
    const float* b1 = (const float*)d_in[3];
    const float* w2 = (const float*)d_in[4];
    const float* b2 = (const float*)d_in[5];
    const float* w3 = (const float*)d_in[6];
    const float* b3 = (const float*)d_in[7];
    const float* w4 = (const float*)d_in[8];
    const float* b4 = (const float*)d_in[9];
    float* out = (float*)d_out;

    char* ws = (char*)d_ws;
    unsigned short* x1nt = (unsigned short*)(ws + 0);
    unsigned short* x2nt = (unsigned short*)(ws + 2359296);
    unsigned short* Abuf = (unsigned short*)(ws + 4718592);
    float* C1f = (float*)(ws + 7372800);
    float* C2f = (float*)(ws + 8699904);
    float* C3f = (float*)(ws + 9031680);
    unsigned short* C1b = (unsigned short*)(ws + 9114624);
    unsigned short* C2b = (unsigned short*)(ws + 9778176);

    hipMemsetAsync(ws + 7372800, 0, 1741824, stream);          // zero C1f..C3f
    knorm<<<128, 256, 0, stream>>>(x1, x2, x1nt, x2nt);
    kcorr<<<64, 256, 0, stream>>>(x1nt, x2nt, Abuf);
    kgemm<5184, 20736, 2592><<<dim3(81, 8), 256, 0, stream>>>(Abuf, w1, C1f);
    kep<5184><<<324, 256, 0, stream>>>(C1f, b1, C1b);
    kgemm<1296, 5184, 288><<<dim3(21, 18), 256, 0, stream>>>(C1b, w2, C2f);
    kep<1296><<<81, 256, 0, stream>>>(C2f, b2, C2b);
    kgemm3<<<dim3(64, 4), 384, 0, stream>>>(C2b, w3, C3f);
    kep3g4<<<64, 384, 0, stream>>>(C3f, b3, w4, b4, out);
}

// Round 2
// 750.541 us; speedup vs baseline: 1.0580x; 1.0580x over previous
//
#include <hip/hip_runtime.h>
#include <stdint.h>
#include <math.h>

// ---------------------------------------------------------------------------
// HNetv1: corr-volume (l2norm + batched 144x128x144 GEMM) -> MLP 20736->5184
// ->1296->324->8, relu/relu/tanh, concat ones -> [64,3,3].
// Dominant cost: reading W1 (430 MB fp32) once -> HBM-bound ~68us floor.
// R2: fused norm+corr (norms factor out of the MFMA: corr = rn2[k]*rn1[ij]*
// <x2_raw, x1_raw>), epilogues fused into consumer GEMMs, nt dropped.
// 6 dispatches: memset, kcorr2, kgemm1, kgemm2f, kgemm3, kep3g4.
// ---------------------------------------------------------------------------

typedef short short8 __attribute__((ext_vector_type(8)));
typedef float f32x4 __attribute__((ext_vector_type(4)));

__device__ __forceinline__ unsigned bf16u(float x) {
    return (__float_as_uint(x) + 0x8000u) >> 16;   // round-half-up to bf16
}
__device__ __forceinline__ unsigned packbf(float a, float b) {
    return ((__float_as_uint(a) + 0x8000u) >> 16) |
           ((__float_as_uint(b) + 0x8000u) & 0xFFFF0000u);
}
__device__ __forceinline__ float bf2f(unsigned short u) {
    return __uint_as_float(((unsigned)u) << 16);
}

// ---------------------------------------------------------------------------
// Fused l2norm + corr. One block per n, 16 waves.
// LDS: raw bf16 x1,x2 transposed to [ij][c], row stride 136 ushorts = 272 B
// (16 B aligned: 272=16*17; dword stride 68 == 4 mod 32 -> b128 frag reads get
// the same uniform 8-slots/bank distribution as contiguous reads).
// corr[k][ij] = rn2[k] * rn1[ij] * sum_c x2raw[k][c]*x1raw[ij][c] via MFMA.
// ---------------------------------------------------------------------------
__global__ __launch_bounds__(1024) void kcorr2(const float* __restrict__ x1,
                                               const float* __restrict__ x2,
                                               unsigned short* __restrict__ Abuf) {
    __shared__ unsigned short s1[144 * 136];
    __shared__ unsigned short s2[144 * 136];
    __shared__ float rn1[144], rn2[144];
    int n = blockIdx.x, t = threadIdx.x;
    const float* p1 = x1 + n * 18432;
    const float* p2 = x2 + n * 18432;
#pragma unroll
    for (int i = 0; i < 18; ++i) {                 // coalesced reads, LDS transpose
        int g = t + 1024 * i;
        int c = g / 144, ij = g - c * 144;
        s1[ij * 136 + c] = (unsigned short)bf16u(p1[g]);
        s2[ij * 136 + c] = (unsigned short)bf16u(p2[g]);
    }
    __syncthreads();
    if (t < 144) {                                  // per-ij channel norms (x1)
        float acc = 0.f;
        for (int c = 0; c < 128; ++c) { float v = bf2f(s1[t * 136 + c]); acc += v * v; }
        rn1[t] = 1.0f / sqrtf(acc);
    } else if (t < 288) {                           // (x2)
        int ij = t - 144;
        float acc = 0.f;
        for (int c = 0; c < 128; ++c) { float v = bf2f(s2[ij * 136 + c]); acc += v * v; }
        rn2[ij] = 1.0f / sqrtf(acc);
    }
    __syncthreads();
    int lane = t & 63, w = t >> 6;
    int col = lane & 15, quad = lane >> 4;
    unsigned short* out = Abuf + n * 20736;
    for (int tt = w; tt < 81; tt += 16) {           // 81 16x16 tiles over 16 waves
        int m0 = (tt / 9) * 16, n0 = (tt % 9) * 16;
        f32x4 acc = {0.f, 0.f, 0.f, 0.f};
        const short8* a0 = (const short8*)(s2 + (m0 + col) * 136 + quad * 8);
        const short8* b0 = (const short8*)(s1 + (n0 + col) * 136 + quad * 8);
#pragma unroll
        for (int ks = 0; ks < 4; ++ks) {            // K=c=128 in 4 MFMA steps
            short8 a = a0[ks * 4];                   // +32 bf16 along c
            short8 bv = b0[ks * 4];
            acc = __builtin_amdgcn_mfma_f32_16x16x32_bf16(a, bv, acc, 0, 0, 0);
        }
        float rc = rn1[n0 + col];
#pragma unroll
        for (int r = 0; r < 4; ++r) {               // C/D: col=lane&15, row=quad*4+r
            int row = m0 + quad * 4 + r;
            out[row * 144 + n0 + col] = (unsigned short)bf16u(acc[r] * rn2[row] * rc);
        }
    }
}

// ---------------------------------------------------------------------------
// Split-K GEMM1: Cf[64][N] += A[64][KTOT](bf16) @ W[KTOT][N](fp32->bf16 otf)
// Block: 4 waves; wave w owns cols [bx*64+w*16, +16), all 64 rows (4 MFMA
// accs). blockIdx.y = K-chunk. fp32 atomics epilogue (8 contenders/addr).
// ---------------------------------------------------------------------------
template <int N, int KTOT, int KCHUNK>
__global__ __launch_bounds__(256) void kgemm(const unsigned short* __restrict__ A,
                                             const float* __restrict__ W,
                                             float* __restrict__ Cf) {
    int lane = threadIdx.x & 63;
    int w = threadIdx.x >> 6;
    int col = lane & 15, quad = lane >> 4;
    int c0 = blockIdx.x * 64 + w * 16;
    int kc = blockIdx.y * KCHUNK;
    const unsigned short* Ap = A + kc + quad * 8;
    const float* Wp = W + (size_t)(kc + quad * 8) * N + c0 + col;
    f32x4 acc0 = {0, 0, 0, 0}, acc1 = {0, 0, 0, 0}, acc2 = {0, 0, 0, 0}, acc3 = {0, 0, 0, 0};
#pragma unroll 2
    for (int ks = 0; ks < KCHUNK / 32; ++ks) {
        int kk = ks * 32;
        short8 a0 = *(const short8*)(Ap + (0 * 16 + col) * KTOT + kk);
        short8 a1 = *(const short8*)(Ap + (1 * 16 + col) * KTOT + kk);
        short8 a2 = *(const short8*)(Ap + (2 * 16 + col) * KTOT + kk);
        short8 a3 = *(const short8*)(Ap + (3 * 16 + col) * KTOT + kk);
        const float* wp = Wp + (size_t)kk * N;
        float b0 = wp[0 * (size_t)N];
        float b1 = wp[1 * (size_t)N];
        float b2 = wp[2 * (size_t)N];
        float b3 = wp[3 * (size_t)N];
        float b4 = wp[4 * (size_t)N];
        float b5 = wp[5 * (size_t)N];
        float b6 = wp[6 * (size_t)N];
        float b7 = wp[7 * (size_t)N];
        union { unsigned u[4]; short8 s; } bu;
        bu.u[0] = packbf(b0, b1);
        bu.u[1] = packbf(b2, b3);
        bu.u[2] = packbf(b4, b5);
        bu.u[3] = packbf(b6, b7);
        acc0 = __builtin_amdgcn_mfma_f32_16x16x32_bf16(a0, bu.s, acc0, 0, 0, 0);
        acc1 = __builtin_amdgcn_mfma_f32_16x16x32_bf16(a1, bu.s, acc1, 0, 0, 0);
        acc2 = __builtin_amdgcn_mfma_f32_16x16x32_bf16(a2, bu.s, acc2, 0, 0, 0);
        acc3 = __builtin_amdgcn_mfma_f32_16x16x32_bf16(a3, bu.s, acc3, 0, 0, 0);
    }
#pragma unroll
    for (int r = 0; r < 4; ++r) {
        int row0 = quad * 4 + r;
        atomicAdd(&Cf[(0 * 16 + row0) * N + c0 + col], acc0[r]);
        atomicAdd(&Cf[(1 * 16 + row0) * N + c0 + col], acc1[r]);
        atomicAdd(&Cf[(2 * 16 + row0) * N + c0 + col], acc2[r]);
        atomicAdd(&Cf[(3 * 16 + row0) * N + c0 + col], acc3[r]);
    }
}

// ---------------------------------------------------------------------------
// GEMM2 with fused layer-1 epilogue: A = bf16(relu(C1f + b1)) built on the fly
// from fp32. Same wave/tile mapping as kgemm. Tail guard for N=1296 (c0>=N).
// ---------------------------------------------------------------------------
template <int N, int KTOT, int KCHUNK>
__global__ __launch_bounds__(256) void kgemm2f(const float* __restrict__ Af,
                                               const float* __restrict__ bias,
                                               const float* __restrict__ W,
                                               float* __restrict__ Cf) {
    int lane = threadIdx.x & 63;
    int w = threadIdx.x >> 6;
    int col = lane & 15, quad = lane >> 4;
    int c0 = blockIdx.x * 64 + w * 16;
    if (c0 >= N) return;                       // no barriers in kernel: safe
    int kc = blockIdx.y * KCHUNK;
    int kb = kc + quad * 8;
    const float* Ap = Af + kb;
    const float* Wp = W + (size_t)kb * N + c0 + col;
    f32x4 acc0 = {0, 0, 0, 0}, acc1 = {0, 0, 0, 0}, acc2 = {0, 0, 0, 0}, acc3 = {0, 0, 0, 0};
#pragma unroll 2
    for (int ks = 0; ks < KCHUNK / 32; ++ks) {
        int kk = ks * 32;
        f32x4 bb0 = *(const f32x4*)(bias + kb + kk);
        f32x4 bb1 = *(const f32x4*)(bias + kb + kk + 4);
        union { unsigned u[4]; short8 s; } au[4];
#pragma unroll
        for (int i = 0; i < 4; ++i) {
            const float* ap = Ap + (size_t)(i * 16 + col) * KTOT + kk;
            f32x4 v0 = *(const f32x4*)(ap);
            f32x4 v1 = *(const f32x4*)(ap + 4);
            float r0 = fmaxf(v0[0] + bb0[0], 0.f), r1 = fmaxf(v0[1] + bb0[1], 0.f);
            float r2 = fmaxf(v0[2] + bb0[2], 0.f), r3 = fmaxf(v0[3] + bb0[3], 0.f);
            float r4 = fmaxf(v1[0] + bb1[0], 0.f), r5 = fmaxf(v1[1] + bb1[1], 0.f);
            float r6 = fmaxf(v1[2] + bb1[2], 0.f), r7 = fmaxf(v1[3] + bb1[3], 0.f);
            au[i].u[0] = packbf(r0, r1); au[i].u[1] = packbf(r2, r3);
            au[i].u[2] = packbf(r4, r5); au[i].u[3] = packbf(r6, r7);
        }
        const float* wp = Wp + (size_t)kk * N;
        float b0 = wp[0 * (size_t)N];
        float b1 = wp[1 * (size_t)N];
        float b2 = wp[2 * (size_t)N];
        float b3 = wp[3 * (size_t)N];
        float b4 = wp[4 * (size_t)N];
        float b5 = wp[5 * (size_t)N];
        float b6 = wp[6 * (size_t)N];
        float b7 = wp[7 * (size_t)N];
        union { unsigned u[4]; short8 s; } bu;
        bu.u[0] = packbf(b0, b1);
        bu.u[1] = packbf(b2, b3);
        bu.u[2] = packbf(b4, b5);
        bu.u[3] = packbf(b6, b7);
        acc0 = __builtin_amdgcn_mfma_f32_16x16x32_bf16(au[0].s, bu.s, acc0, 0, 0, 0);
        acc1 = __builtin_amdgcn_mfma_f32_16x16x32_bf16(au[1].s, bu.s, acc1, 0, 0, 0);
        acc2 = __builtin_amdgcn_mfma_f32_16x16x32_bf16(au[2].s, bu.s, acc2, 0, 0, 0);
        acc3 = __builtin_amdgcn_mfma_f32_16x16x32_bf16(au[3].s, bu.s, acc3, 0, 0, 0);
    }
#pragma unroll
    for (int r = 0; r < 4; ++r) {
        int row0 = quad * 4 + r;
        atomicAdd(&Cf[(0 * 16 + row0) * N + c0 + col], acc0[r]);
        atomicAdd(&Cf[(1 * 16 + row0) * N + c0 + col], acc1[r]);
        atomicAdd(&Cf[(2 * 16 + row0) * N + c0 + col], acc2[r]);
        atomicAdd(&Cf[(3 * 16 + row0) * N + c0 + col], acc3[r]);
    }
}

// ---------------------------------------------------------------------------
// GEMM3 with fused layer-2 epilogue: a[k] = relu(C2f+b2) staged fp32 in LDS
// (broadcast reads), W3 coalesced, k-split by 4 with atomics into C3f.
// ---------------------------------------------------------------------------
__global__ __launch_bounds__(384) void kgemm3(const float* __restrict__ C2f,
                                              const float* __restrict__ b2,
                                              const float* __restrict__ W3,
                                              float* __restrict__ C3f) {
    __shared__ float as[324];
    int n = blockIdx.x, sl = blockIdx.y;
    int t = threadIdx.x;
    if (t < 324) as[t] = fmaxf(C2f[n * 1296 + sl * 324 + t] + b2[sl * 324 + t], 0.f);
    __syncthreads();
    if (t < 324) {
        float acc = 0.f;
        const float* wp = W3 + sl * 324 * 324 + t;
#pragma unroll 4
        for (int k = 0; k < 324; ++k) acc += as[k] * wp[k * 324];
        atomicAdd(&C3f[n * 324 + t], acc);
    }
}

// ---------------------------------------------------------------------------
// Epilogue3 + GEMM4 fused: t3 = tanh(C3f + b3) (LDS), H = t3 @ W4 + b4,
// out[n] = [H(8), 1] -> 9 floats.
// ---------------------------------------------------------------------------
__global__ __launch_bounds__(384) void kep3g4(const float* __restrict__ C3f,
                                              const float* __restrict__ b3,
                                              const float* __restrict__ W4,
                                              const float* __restrict__ b4,
                                              float* __restrict__ out) {
    __shared__ float t3[324];
    int n = blockIdx.x, t = threadIdx.x;
    if (t < 324) t3[t] = tanhf(C3f[n * 324 + t] + b3[t]);
    __syncthreads();
    if (t < 8) {
        float acc = b4[t];
        for (int k = 0; k < 324; ++k) acc += t3[k] * W4[k * 8 + t];
        out[n * 9 + t] = acc;
    } else if (t == 8) {
        out[n * 9 + 8] = 1.0f;
    }
}

// ---------------------------------------------------------------------------
// Workspace layout (bytes):
//   Abuf @ 0        2654208  bf16 [64][20736]
//   C1f  @ 2654208  1327104  f32  [64][5184]  \
//   C2f  @ 3981312   331776  f32  [64][1296]   } one memset (1741824 B)
//   C3f  @ 4313088    82944  f32  [64][324]   /
// total ~4.4 MB
// ---------------------------------------------------------------------------
extern "C" void kernel_launch(void* const* d_in, const int* in_sizes, int n_in,
                              void* d_out, int out_size, void* d_ws, size_t ws_size,
                              hipStream_t stream) {
    const float* x1 = (const float*)d_in[0];
    const float* x2 = (const float*)d_in[1];
    const float* w1 = (const float*)d_in[2];
    const float* b1 = (const float*)d_in[3];
    const float* w2 = (const float*)d_in[4];
    const float* b2 = (const float*)d_in[5];
    const float* w3 = (const float*)d_in[6];
    const float* b3 = (const float*)d_in[7];
    const float* w4 = (const float*)d_in[8];
    const float* b4 = (const float*)d_in[9];
    float* out = (float*)d_out;

    char* ws = (char*)d_ws;
    unsigned short* Abuf = (unsigned short*)(ws + 0);
    float* C1f = (float*)(ws + 2654208);
    float* C2f = (float*)(ws + 3981312);
    float* C3f = (float*)(ws + 4313088);

    hipMemsetAsync(ws + 2654208, 0, 1741824, stream);   // zero C1f..C3f
    kcorr2<<<64, 1024, 0, stream>>>(x1, x2, Abuf);
    kgemm<5184, 20736, 2592><<<dim3(81, 8), 256, 0, stream>>>(Abuf, w1, C1f);
    kgemm2f<1296, 5184, 288><<<dim3(21, 18), 256, 0, stream>>>(C1f, b1, w2, C2f);
    kgemm3<<<dim3(64, 4), 384, 0, stream>>>(C2f, b2, w3, C3f);
    kep3g4<<<64, 384, 0, stream>>>(C3f, b3, w4, b4, out);
}

// Round 3
// 679.603 us; speedup vs baseline: 1.1685x; 1.1044x over previous
//
#include <hip/hip_runtime.h>
#include <stdint.h>
#include <math.h>

// ---------------------------------------------------------------------------
// HNetv1: corr-volume (l2norm + batched 144x128x144 GEMM) -> MLP 20736->5184
// ->1296->324->8, relu/relu/tanh, concat ones -> [64,3,3].
// Dominant cost: reading W1 (430 MB fp32) once -> HBM-bound ~68us floor.
// R3: kgemm1 split-K y=18 (tail balance), kcorr2 192 blocks (3 m-parts/n),
// kgemm3 y=8 split, kep3g4 wave-parallel reduction, kgemm2f y=27.
// ---------------------------------------------------------------------------

typedef short short8 __attribute__((ext_vector_type(8)));
typedef float f32x4 __attribute__((ext_vector_type(4)));

__device__ __forceinline__ unsigned bf16u(float x) {
    return (__float_as_uint(x) + 0x8000u) >> 16;   // round-half-up to bf16
}
__device__ __forceinline__ unsigned packbf(float a, float b) {
    return ((__float_as_uint(a) + 0x8000u) >> 16) |
           ((__float_as_uint(b) + 0x8000u) & 0xFFFF0000u);
}
__device__ __forceinline__ float bf2f(unsigned short u) {
    return __uint_as_float(((unsigned)u) << 16);
}

// ---------------------------------------------------------------------------
// Fused l2norm + corr, 3 m-parts per n (192 blocks, 16 waves each).
// LDS: raw bf16 x1 full [144][c], x2 part [48][c], row stride 136 ushorts.
// corr[k][ij] = rn2[k]*rn1[ij]*<x2raw[k],x1raw[ij]> via MFMA (norms factor).
// ---------------------------------------------------------------------------
__global__ __launch_bounds__(1024) void kcorr2(const float* __restrict__ x1,
                                               const float* __restrict__ x2,
                                               unsigned short* __restrict__ Abuf) {
    __shared__ unsigned short s1[144 * 136];
    __shared__ unsigned short s2p[48 * 136];
    __shared__ float rn1[144], rn2p[48];
    int b = blockIdx.x;
    int n = b / 3, p = b - n * 3;           // part p owns corr rows [48p, 48p+48)
    int t = threadIdx.x;
    const float* p1 = x1 + n * 18432;
    const float* p2 = x2 + n * 18432;
#pragma unroll
    for (int i = 0; i < 18; ++i) {          // x1 full: coalesced, LDS transpose
        int g = t + 1024 * i;
        int c = g / 144, ij = g - c * 144;
        s1[ij * 136 + c] = (unsigned short)bf16u(p1[g]);
    }
#pragma unroll
    for (int i = 0; i < 6; ++i) {           // x2 part: 128c x 48ij, 192B runs
        int g = t + 1024 * i;
        int c = g / 48, ijl = g - c * 48;
        s2p[ijl * 136 + c] = (unsigned short)bf16u(p2[c * 144 + p * 48 + ijl]);
    }
    __syncthreads();
    if (t < 144) {                           // rn1: all ij (needed for all cols)
        float acc = 0.f;
        for (int c = 0; c < 128; ++c) { float v = bf2f(s1[t * 136 + c]); acc += v * v; }
        rn1[t] = 1.0f / sqrtf(acc);
    } else if (t < 192) {                    // rn2: this part's 48 rows
        int ijl = t - 144;
        float acc = 0.f;
        for (int c = 0; c < 128; ++c) { float v = bf2f(s2p[ijl * 136 + c]); acc += v * v; }
        rn2p[ijl] = 1.0f / sqrtf(acc);
    }
    __syncthreads();
    int lane = t & 63, w = t >> 6;
    int col = lane & 15, quad = lane >> 4;
    unsigned short* out = Abuf + n * 20736 + p * 48 * 144;
    for (int tt = w; tt < 27; tt += 16) {    // 3 m-tiles x 9 n-tiles
        int ml0 = (tt / 9) * 16, n0 = (tt % 9) * 16;
        f32x4 acc = {0.f, 0.f, 0.f, 0.f};
        const short8* a0 = (const short8*)(s2p + (ml0 + col) * 136 + quad * 8);
        const short8* b0 = (const short8*)(s1 + (n0 + col) * 136 + quad * 8);
#pragma unroll
        for (int ks = 0; ks < 4; ++ks) {     // K=c=128 in 4 MFMA steps
            short8 a = a0[ks * 4];
            short8 bv = b0[ks * 4];
            acc = __builtin_amdgcn_mfma_f32_16x16x32_bf16(a, bv, acc, 0, 0, 0);
        }
        float rc = rn1[n0 + col];
#pragma unroll
        for (int r = 0; r < 4; ++r) {        // C/D: col=lane&15, row=quad*4+r
            int rl = ml0 + quad * 4 + r;
            out[rl * 144 + n0 + col] = (unsigned short)bf16u(acc[r] * rn2p[rl] * rc);
        }
    }
}

// ---------------------------------------------------------------------------
// Split-K GEMM1: Cf[64][N] += A[64][KTOT](bf16) @ W[KTOT][N](fp32->bf16 otf)
// 4 waves/block; wave w owns cols [bx*64+w*16,+16), all 64 rows (4 MFMA accs).
// blockIdx.y = K-chunk (18 chunks of 1152). fp32 atomics epilogue.
// ---------------------------------------------------------------------------
template <int N, int KTOT, int KCHUNK>
__global__ __launch_bounds__(256) void kgemm(const unsigned short* __restrict__ A,
                                             const float* __restrict__ W,
                                             float* __restrict__ Cf) {
    int lane = threadIdx.x & 63;
    int w = threadIdx.x >> 6;
    int col = lane & 15, quad = lane >> 4;
    int c0 = blockIdx.x * 64 + w * 16;
    int kc = blockIdx.y * KCHUNK;
    const unsigned short* Ap = A + kc + quad * 8;
    const float* Wp = W + (size_t)(kc + quad * 8) * N + c0 + col;
    f32x4 acc0 = {0, 0, 0, 0}, acc1 = {0, 0, 0, 0}, acc2 = {0, 0, 0, 0}, acc3 = {0, 0, 0, 0};
#pragma unroll 2
    for (int ks = 0; ks < KCHUNK / 32; ++ks) {
        int kk = ks * 32;
        short8 a0 = *(const short8*)(Ap + (0 * 16 + col) * KTOT + kk);
        short8 a1 = *(const short8*)(Ap + (1 * 16 + col) * KTOT + kk);
        short8 a2 = *(const short8*)(Ap + (2 * 16 + col) * KTOT + kk);
        short8 a3 = *(const short8*)(Ap + (3 * 16 + col) * KTOT + kk);
        const float* wp = Wp + (size_t)kk * N;
        float b0 = wp[0 * (size_t)N];
        float b1 = wp[1 * (size_t)N];
        float b2 = wp[2 * (size_t)N];
        float b3 = wp[3 * (size_t)N];
        float b4 = wp[4 * (size_t)N];
        float b5 = wp[5 * (size_t)N];
        float b6 = wp[6 * (size_t)N];
        float b7 = wp[7 * (size_t)N];
        union { unsigned u[4]; short8 s; } bu;
        bu.u[0] = packbf(b0, b1);
        bu.u[1] = packbf(b2, b3);
        bu.u[2] = packbf(b4, b5);
        bu.u[3] = packbf(b6, b7);
        acc0 = __builtin_amdgcn_mfma_f32_16x16x32_bf16(a0, bu.s, acc0, 0, 0, 0);
        acc1 = __builtin_amdgcn_mfma_f32_16x16x32_bf16(a1, bu.s, acc1, 0, 0, 0);
        acc2 = __builtin_amdgcn_mfma_f32_16x16x32_bf16(a2, bu.s, acc2, 0, 0, 0);
        acc3 = __builtin_amdgcn_mfma_f32_16x16x32_bf16(a3, bu.s, acc3, 0, 0, 0);
    }
#pragma unroll
    for (int r = 0; r < 4; ++r) {
        int row0 = quad * 4 + r;
        atomicAdd(&Cf[(0 * 16 + row0) * N + c0 + col], acc0[r]);
        atomicAdd(&Cf[(1 * 16 + row0) * N + c0 + col], acc1[r]);
        atomicAdd(&Cf[(2 * 16 + row0) * N + c0 + col], acc2[r]);
        atomicAdd(&Cf[(3 * 16 + row0) * N + c0 + col], acc3[r]);
    }
}

// ---------------------------------------------------------------------------
// GEMM2 with fused layer-1 epilogue: A = bf16(relu(C1f + b1)) on the fly.
// Tail guard for N=1296 (c0>=N); no barriers so early return is safe.
// ---------------------------------------------------------------------------
template <int N, int KTOT, int KCHUNK>
__global__ __launch_bounds__(256) void kgemm2f(const float* __restrict__ Af,
                                               const float* __restrict__ bias,
                                               const float* __restrict__ W,
                                               float* __restrict__ Cf) {
    int lane = threadIdx.x & 63;
    int w = threadIdx.x >> 6;
    int col = lane & 15, quad = lane >> 4;
    int c0 = blockIdx.x * 64 + w * 16;
    if (c0 >= N) return;
    int kc = blockIdx.y * KCHUNK;
    int kb = kc + quad * 8;
    const float* Ap = Af + kb;
    const float* Wp = W + (size_t)kb * N + c0 + col;
    f32x4 acc0 = {0, 0, 0, 0}, acc1 = {0, 0, 0, 0}, acc2 = {0, 0, 0, 0}, acc3 = {0, 0, 0, 0};
#pragma unroll 2
    for (int ks = 0; ks < KCHUNK / 32; ++ks) {
        int kk = ks * 32;
        f32x4 bb0 = *(const f32x4*)(bias + kb + kk);
        f32x4 bb1 = *(const f32x4*)(bias + kb + kk + 4);
        union { unsigned u[4]; short8 s; } au[4];
#pragma unroll
        for (int i = 0; i < 4; ++i) {
            const float* ap = Ap + (size_t)(i * 16 + col) * KTOT + kk;
            f32x4 v0 = *(const f32x4*)(ap);
            f32x4 v1 = *(const f32x4*)(ap + 4);
            float r0 = fmaxf(v0[0] + bb0[0], 0.f), r1 = fmaxf(v0[1] + bb0[1], 0.f);
            float r2 = fmaxf(v0[2] + bb0[2], 0.f), r3 = fmaxf(v0[3] + bb0[3], 0.f);
            float r4 = fmaxf(v1[0] + bb1[0], 0.f), r5 = fmaxf(v1[1] + bb1[1], 0.f);
            float r6 = fmaxf(v1[2] + bb1[2], 0.f), r7 = fmaxf(v1[3] + bb1[3], 0.f);
            au[i].u[0] = packbf(r0, r1); au[i].u[1] = packbf(r2, r3);
            au[i].u[2] = packbf(r4, r5); au[i].u[3] = packbf(r6, r7);
        }
        const float* wp = Wp + (size_t)kk * N;
        float b0 = wp[0 * (size_t)N];
        float b1 = wp[1 * (size_t)N];
        float b2 = wp[2 * (size_t)N];
        float b3 = wp[3 * (size_t)N];
        float b4 = wp[4 * (size_t)N];
        float b5 = wp[5 * (size_t)N];
        float b6 = wp[6 * (size_t)N];
        float b7 = wp[7 * (size_t)N];
        union { unsigned u[4]; short8 s; } bu;
        bu.u[0] = packbf(b0, b1);
        bu.u[1] = packbf(b2, b3);
        bu.u[2] = packbf(b4, b5);
        bu.u[3] = packbf(b6, b7);
        acc0 = __builtin_amdgcn_mfma_f32_16x16x32_bf16(au[0].s, bu.s, acc0, 0, 0, 0);
        acc1 = __builtin_amdgcn_mfma_f32_16x16x32_bf16(au[1].s, bu.s, acc1, 0, 0, 0);
        acc2 = __builtin_amdgcn_mfma_f32_16x16x32_bf16(au[2].s, bu.s, acc2, 0, 0, 0);
        acc3 = __builtin_amdgcn_mfma_f32_16x16x32_bf16(au[3].s, bu.s, acc3, 0, 0, 0);
    }
#pragma unroll
    for (int r = 0; r < 4; ++r) {
        int row0 = quad * 4 + r;
        atomicAdd(&Cf[(0 * 16 + row0) * N + c0 + col], acc0[r]);
        atomicAdd(&Cf[(1 * 16 + row0) * N + c0 + col], acc1[r]);
        atomicAdd(&Cf[(2 * 16 + row0) * N + c0 + col], acc2[r]);
        atomicAdd(&Cf[(3 * 16 + row0) * N + c0 + col], acc3[r]);
    }
}

// ---------------------------------------------------------------------------
// GEMM3 with fused layer-2 epilogue: a[k] = relu(C2f+b2) staged fp32 in LDS,
// W3 coalesced (stride-324 full-wave rows), k-split by 8 with atomics.
// ---------------------------------------------------------------------------
__global__ __launch_bounds__(384) void kgemm3(const float* __restrict__ C2f,
                                              const float* __restrict__ b2,
                                              const float* __restrict__ W3,
                                              float* __restrict__ C3f) {
    __shared__ float as[162];
    int n = blockIdx.x, sl = blockIdx.y;     // sl in [0,8): k-slice of 162
    int t = threadIdx.x;
    int base = sl * 162;
    if (t < 162) as[t] = fmaxf(C2f[n * 1296 + base + t] + b2[base + t], 0.f);
    __syncthreads();
    if (t < 324) {
        float acc = 0.f;
        const float* wp = W3 + (size_t)base * 324 + t;
#pragma unroll 6
        for (int k = 0; k < 162; ++k) acc += as[k] * wp[k * 324];
        atomicAdd(&C3f[n * 324 + t], acc);
    }
}

// ---------------------------------------------------------------------------
// Epilogue3 + GEMM4: t3 = tanh(C3f + b3) (LDS), wave-parallel dot: lane l
// accumulates 8 partial outputs over k = l, l+64, ...; LDS tree to 8 outs.
// ---------------------------------------------------------------------------
__global__ __launch_bounds__(128) void kep3g4(const float* __restrict__ C3f,
                                              const float* __restrict__ b3,
                                              const float* __restrict__ W4,
                                              const float* __restrict__ b4,
                                              float* __restrict__ out) {
    __shared__ float t3[324];
    __shared__ float part[64][8];
    int n = blockIdx.x, t = threadIdx.x;
    for (int i = t; i < 324; i += 128) t3[i] = tanhf(C3f[n * 324 + i] + b3[i]);
    __syncthreads();
    if (t < 64) {
        float acc[8];
#pragma unroll
        for (int j = 0; j < 8; ++j) acc[j] = 0.f;
#pragma unroll
        for (int kk = 0; kk < 6; ++kk) {
            int k = t + 64 * kk;
            if (k < 324) {
                float v = t3[k];
                f32x4 w0 = *(const f32x4*)(W4 + k * 8);
                f32x4 w1 = *(const f32x4*)(W4 + k * 8 + 4);
                acc[0] += v * w0[0]; acc[1] += v * w0[1];
                acc[2] += v * w0[2]; acc[3] += v * w0[3];
                acc[4] += v * w1[0]; acc[5] += v * w1[1];
                acc[6] += v * w1[2]; acc[7] += v * w1[3];
            }
        }
#pragma unroll
        for (int j = 0; j < 8; ++j) part[t][j] = acc[j];
    }
    __syncthreads();
    if (t < 8) {
        float acc = b4[t];
        for (int l = 0; l < 64; ++l) acc += part[l][t];
        out[n * 9 + t] = acc;
    } else if (t == 8) {
        out[n * 9 + 8] = 1.0f;
    }
}

// ---------------------------------------------------------------------------
// Workspace layout (bytes):
//   Abuf @ 0        2654208  bf16 [64][20736]
//   C1f  @ 2654208  1327104  f32  [64][5184]  \
//   C2f  @ 3981312   331776  f32  [64][1296]   } one memset (1741824 B)
//   C3f  @ 4313088    82944  f32  [64][324]   /
// ---------------------------------------------------------------------------
extern "C" void kernel_launch(void* const* d_in, const int* in_sizes, int n_in,
                              void* d_out, int out_size, void* d_ws, size_t ws_size,
                              hipStream_t stream) {
    const float* x1 = (const float*)d_in[0];
    const float* x2 = (const float*)d_in[1];
    const float* w1 = (const float*)d_in[2];
    const float* b1 = (const float*)d_in[3];
    const float* w2 = (const float*)d_in[4];
    const float* b2 = (const float*)d_in[5];
    const float* w3 = (const float*)d_in[6];
    const float* b3 = (const float*)d_in[7];
    const float* w4 = (const float*)d_in[8];
    const float* b4 = (const float*)d_in[9];
    float* out = (float*)d_out;

    char* ws = (char*)d_ws;
    unsigned short* Abuf = (unsigned short*)(ws + 0);
    float* C1f = (float*)(ws + 2654208);
    float* C2f = (float*)(ws + 3981312);
    float* C3f = (float*)(ws + 4313088);

    hipMemsetAsync(ws + 2654208, 0, 1741824, stream);   // zero C1f..C3f
    kcorr2<<<192, 1024, 0, stream>>>(x1, x2, Abuf);
    kgemm<5184, 20736, 1152><<<dim3(81, 18), 256, 0, stream>>>(Abuf, w1, C1f);
    kgemm2f<1296, 5184, 192><<<dim3(21, 27), 256, 0, stream>>>(C1f, b1, w2, C2f);
    kgemm3<<<dim3(64, 8), 384, 0, stream>>>(C2f, b2, w3, C3f);
    kep3g4<<<64, 128, 0, stream>>>(C3f, b3, w4, b4, out);
}

// Round 4
// 671.898 us; speedup vs baseline: 1.1819x; 1.0115x over previous
//
#include <hip/hip_runtime.h>
#include <stdint.h>
#include <math.h>

// ---------------------------------------------------------------------------
// HNetv1: corr-volume (l2norm + batched 144x128x144 GEMM) -> MLP 20736->5184
// ->1296->324->8, relu/relu/tanh, concat ones -> [64,3,3].
// Dominant cost: reading W1 (430 MB fp32) once -> HBM-bound ~68us floor.
// R4: K-packed activation layout  idx = (f>>5)*2048 + batch*32 + (f&31)
// for Abuf/C1f/C2f so every MFMA A-frag load is 16B-contiguous per lane
// (1KB coalesced per wave instr) instead of 16 scattered 64B requests.
// ---------------------------------------------------------------------------

typedef short short8 __attribute__((ext_vector_type(8)));
typedef float f32x4 __attribute__((ext_vector_type(4)));

__device__ __forceinline__ unsigned bf16u(float x) {
    return (__float_as_uint(x) + 0x8000u) >> 16;   // round-half-up to bf16
}
__device__ __forceinline__ unsigned packbf(float a, float b) {
    return ((__float_as_uint(a) + 0x8000u) >> 16) |
           ((__float_as_uint(b) + 0x8000u) & 0xFFFF0000u);
}
__device__ __forceinline__ float bf2f(unsigned short u) {
    return __uint_as_float(((unsigned)u) << 16);
}

// ---------------------------------------------------------------------------
// Fused l2norm + corr, 3 m-parts per n (192 blocks, 16 waves each).
// LDS: raw bf16 x1 full [144][c], x2 part [48][c], row stride 136 ushorts.
// corr[k][ij] = rn2[k]*rn1[ij]*<x2raw[k],x1raw[ij]> via MFMA (norms factor).
// Output written K-packed: A[(f>>5)*2048 + n*32 + (f&31)], f = k*144 + ij.
// ---------------------------------------------------------------------------
__global__ __launch_bounds__(1024) void kcorr2(const float* __restrict__ x1,
                                               const float* __restrict__ x2,
                                               unsigned short* __restrict__ Abuf) {
    __shared__ unsigned short s1[144 * 136];
    __shared__ unsigned short s2p[48 * 136];
    __shared__ float rn1[144], rn2p[48];
    int b = blockIdx.x;
    int n = b / 3, p = b - n * 3;           // part p owns corr rows [48p, 48p+48)
    int t = threadIdx.x;
    const float* p1 = x1 + n * 18432;
    const float* p2 = x2 + n * 18432;
#pragma unroll
    for (int i = 0; i < 18; ++i) {          // x1 full: coalesced, LDS transpose
        int g = t + 1024 * i;
        int c = g / 144, ij = g - c * 144;
        s1[ij * 136 + c] = (unsigned short)bf16u(p1[g]);
    }
#pragma unroll
    for (int i = 0; i < 6; ++i) {           // x2 part: 128c x 48ij, 192B runs
        int g = t + 1024 * i;
        int c = g / 48, ijl = g - c * 48;
        s2p[ijl * 136 + c] = (unsigned short)bf16u(p2[c * 144 + p * 48 + ijl]);
    }
    __syncthreads();
    if (t < 144) {                           // rn1: all ij (needed for all cols)
        float acc = 0.f;
        for (int c = 0; c < 128; ++c) { float v = bf2f(s1[t * 136 + c]); acc += v * v; }
        rn1[t] = 1.0f / sqrtf(acc);
    } else if (t < 192) {                    // rn2: this part's 48 rows
        int ijl = t - 144;
        float acc = 0.f;
        for (int c = 0; c < 128; ++c) { float v = bf2f(s2p[ijl * 136 + c]); acc += v * v; }
        rn2p[ijl] = 1.0f / sqrtf(acc);
    }
    __syncthreads();
    int lane = t & 63, w = t >> 6;
    int col = lane & 15, quad = lane >> 4;
    for (int tt = w; tt < 27; tt += 16) {    // 3 m-tiles x 9 n-tiles
        int ml0 = (tt / 9) * 16, n0 = (tt % 9) * 16;
        f32x4 acc = {0.f, 0.f, 0.f, 0.f};
        const short8* a0 = (const short8*)(s2p + (ml0 + col) * 136 + quad * 8);
        const short8* b0 = (const short8*)(s1 + (n0 + col) * 136 + quad * 8);
#pragma unroll
        for (int ks = 0; ks < 4; ++ks) {     // K=c=128 in 4 MFMA steps
            short8 a = a0[ks * 4];
            short8 bv = b0[ks * 4];
            acc = __builtin_amdgcn_mfma_f32_16x16x32_bf16(a, bv, acc, 0, 0, 0);
        }
        float rc = rn1[n0 + col];
#pragma unroll
        for (int r = 0; r < 4; ++r) {        // C/D: col=lane&15, row=quad*4+r
            int rl = ml0 + quad * 4 + r;
            int f = (p * 48 + rl) * 144 + n0 + col;     // feature index
            Abuf[(size_t)(f >> 5) * 2048 + n * 32 + (f & 31)] =
                (unsigned short)bf16u(acc[r] * rn2p[rl] * rc);
        }
    }
}

// ---------------------------------------------------------------------------
// Split-K GEMM1: Cf += A(K-packed bf16) @ W[KTOT][N](fp32->bf16 otf).
// A-frag load: ap + (i*16+col)*32 + quad*8 -> 16B/lane, 1KB/wave coalesced.
// Output Cf also K-packed over its out-features. fp32 atomics epilogue.
// ---------------------------------------------------------------------------
template <int N, int KTOT, int KCHUNK>
__global__ __launch_bounds__(256) void kgemm(const unsigned short* __restrict__ A,
                                             const float* __restrict__ W,
                                             float* __restrict__ Cf) {
    int lane = threadIdx.x & 63;
    int w = threadIdx.x >> 6;
    int col = lane & 15, quad = lane >> 4;
    int c0 = blockIdx.x * 64 + w * 16;
    int kc = blockIdx.y * KCHUNK;
    const unsigned short* Ap = A + (size_t)(kc >> 5) * 2048 + quad * 8;
    const float* Wp = W + (size_t)(kc + quad * 8) * N + c0 + col;
    f32x4 acc0 = {0, 0, 0, 0}, acc1 = {0, 0, 0, 0}, acc2 = {0, 0, 0, 0}, acc3 = {0, 0, 0, 0};
#pragma unroll 2
    for (int ks = 0; ks < KCHUNK / 32; ++ks) {
        const unsigned short* ap = Ap + ks * 2048;
        short8 a0 = *(const short8*)(ap + (0 * 16 + col) * 32);
        short8 a1 = *(const short8*)(ap + (1 * 16 + col) * 32);
        short8 a2 = *(const short8*)(ap + (2 * 16 + col) * 32);
        short8 a3 = *(const short8*)(ap + (3 * 16 + col) * 32);
        const float* wp = Wp + (size_t)(ks * 32) * N;
        float b0 = wp[0 * (size_t)N];
        float b1 = wp[1 * (size_t)N];
        float b2 = wp[2 * (size_t)N];
        float b3 = wp[3 * (size_t)N];
        float b4 = wp[4 * (size_t)N];
        float b5 = wp[5 * (size_t)N];
        float b6 = wp[6 * (size_t)N];
        float b7 = wp[7 * (size_t)N];
        union { unsigned u[4]; short8 s; } bu;
        bu.u[0] = packbf(b0, b1);
        bu.u[1] = packbf(b2, b3);
        bu.u[2] = packbf(b4, b5);
        bu.u[3] = packbf(b6, b7);
        acc0 = __builtin_amdgcn_mfma_f32_16x16x32_bf16(a0, bu.s, acc0, 0, 0, 0);
        acc1 = __builtin_amdgcn_mfma_f32_16x16x32_bf16(a1, bu.s, acc1, 0, 0, 0);
        acc2 = __builtin_amdgcn_mfma_f32_16x16x32_bf16(a2, bu.s, acc2, 0, 0, 0);
        acc3 = __builtin_amdgcn_mfma_f32_16x16x32_bf16(a3, bu.s, acc3, 0, 0, 0);
    }
    int f = c0 + col;                                   // out-feature, K-packed
    float* cb = Cf + (size_t)(f >> 5) * 2048 + (f & 31);
#pragma unroll
    for (int r = 0; r < 4; ++r) {
        int row0 = quad * 4 + r;
        atomicAdd(cb + (0 * 16 + row0) * 32, acc0[r]);
        atomicAdd(cb + (1 * 16 + row0) * 32, acc1[r]);
        atomicAdd(cb + (2 * 16 + row0) * 32, acc2[r]);
        atomicAdd(cb + (3 * 16 + row0) * 32, acc3[r]);
    }
}

// ---------------------------------------------------------------------------
// GEMM2, fused layer-1 epilogue: A = bf16(relu(C1f(K-packed fp32) + b1)) on
// the fly; A-frag loads = 2x f32x4 contiguous per lane. Out K-packed too.
// ---------------------------------------------------------------------------
template <int N, int KTOT, int KCHUNK>
__global__ __launch_bounds__(256) void kgemm2f(const float* __restrict__ Af,
                                               const float* __restrict__ bias,
                                               const float* __restrict__ W,
                                               float* __restrict__ Cf) {
    int lane = threadIdx.x & 63;
    int w = threadIdx.x >> 6;
    int col = lane & 15, quad = lane >> 4;
    int c0 = blockIdx.x * 64 + w * 16;
    if (c0 >= N) return;                       // no barriers in kernel: safe
    int kc = blockIdx.y * KCHUNK;
    const float* Wp = W + (size_t)(kc + quad * 8) * N + c0 + col;
    f32x4 acc0 = {0, 0, 0, 0}, acc1 = {0, 0, 0, 0}, acc2 = {0, 0, 0, 0}, acc3 = {0, 0, 0, 0};
#pragma unroll 2
    for (int ks = 0; ks < KCHUNK / 32; ++ks) {
        int kk = ks * 32;
        f32x4 bb0 = *(const f32x4*)(bias + kc + kk + quad * 8);
        f32x4 bb1 = *(const f32x4*)(bias + kc + kk + quad * 8 + 4);
        const float* ab = Af + (size_t)((kc + kk) >> 5) * 2048 + quad * 8;
        union { unsigned u[4]; short8 s; } au[4];
#pragma unroll
        for (int i = 0; i < 4; ++i) {
            const float* ap = ab + (i * 16 + col) * 32;
            f32x4 v0 = *(const f32x4*)(ap);
            f32x4 v1 = *(const f32x4*)(ap + 4);
            float r0 = fmaxf(v0[0] + bb0[0], 0.f), r1 = fmaxf(v0[1] + bb0[1], 0.f);
            float r2 = fmaxf(v0[2] + bb0[2], 0.f), r3 = fmaxf(v0[3] + bb0[3], 0.f);
            float r4 = fmaxf(v1[0] + bb1[0], 0.f), r5 = fmaxf(v1[1] + bb1[1], 0.f);
            float r6 = fmaxf(v1[2] + bb1[2], 0.f), r7 = fmaxf(v1[3] + bb1[3], 0.f);
            au[i].u[0] = packbf(r0, r1); au[i].u[1] = packbf(r2, r3);
            au[i].u[2] = packbf(r4, r5); au[i].u[3] = packbf(r6, r7);
        }
        const float* wp = Wp + (size_t)kk * N;
        float b0 = wp[0 * (size_t)N];
        float b1 = wp[1 * (size_t)N];
        float b2 = wp[2 * (size_t)N];
        float b3 = wp[3 * (size_t)N];
        float b4 = wp[4 * (size_t)N];
        float b5 = wp[5 * (size_t)N];
        float b6 = wp[6 * (size_t)N];
        float b7 = wp[7 * (size_t)N];
        union { unsigned u[4]; short8 s; } bu;
        bu.u[0] = packbf(b0, b1);
        bu.u[1] = packbf(b2, b3);
        bu.u[2] = packbf(b4, b5);
        bu.u[3] = packbf(b6, b7);
        acc0 = __builtin_amdgcn_mfma_f32_16x16x32_bf16(au[0].s, bu.s, acc0, 0, 0, 0);
        acc1 = __builtin_amdgcn_mfma_f32_16x16x32_bf16(au[1].s, bu.s, acc1, 0, 0, 0);
        acc2 = __builtin_amdgcn_mfma_f32_16x16x32_bf16(au[2].s, bu.s, acc2, 0, 0, 0);
        acc3 = __builtin_amdgcn_mfma_f32_16x16x32_bf16(au[3].s, bu.s, acc3, 0, 0, 0);
    }
    int f = c0 + col;                                   // out-feature, K-packed
    float* cb = Cf + (size_t)(f >> 5) * 2048 + (f & 31);
#pragma unroll
    for (int r = 0; r < 4; ++r) {
        int row0 = quad * 4 + r;
        atomicAdd(cb + (0 * 16 + row0) * 32, acc0[r]);
        atomicAdd(cb + (1 * 16 + row0) * 32, acc1[r]);
        atomicAdd(cb + (2 * 16 + row0) * 32, acc2[r]);
        atomicAdd(cb + (3 * 16 + row0) * 32, acc3[r]);
    }
}

// ---------------------------------------------------------------------------
// GEMM3, fused layer-2 epilogue: a[k] = relu(C2f(K-packed)+b2) staged in LDS,
// W3 coalesced (stride-324 rows), k-split by 8 with atomics into C3f (linear).
// ---------------------------------------------------------------------------
__global__ __launch_bounds__(384) void kgemm3(const float* __restrict__ C2f,
                                              const float* __restrict__ b2,
                                              const float* __restrict__ W3,
                                              float* __restrict__ C3f) {
    __shared__ float as[162];
    int n = blockIdx.x, sl = blockIdx.y;     // sl in [0,8): k-slice of 162
    int t = threadIdx.x;
    int base = sl * 162;
    if (t < 162) {
        int k = base + t;
        float v = C2f[(size_t)(k >> 5) * 2048 + n * 32 + (k & 31)];
        as[t] = fmaxf(v + b2[k], 0.f);
    }
    __syncthreads();
    if (t < 324) {
        float acc = 0.f;
        const float* wp = W3 + (size_t)base * 324 + t;
#pragma unroll 6
        for (int k = 0; k < 162; ++k) acc += as[k] * wp[k * 324];
        atomicAdd(&C3f[n * 324 + t], acc);
    }
}

// ---------------------------------------------------------------------------
// Epilogue3 + GEMM4: t3 = tanh(C3f + b3) (LDS), wave-parallel dot: lane l
// accumulates 8 partial outputs over k = l, l+64, ...; LDS tree to 8 outs.
// ---------------------------------------------------------------------------
__global__ __launch_bounds__(128) void kep3g4(const float* __restrict__ C3f,
                                              const float* __restrict__ b3,
                                              const float* __restrict__ W4,
                                              const float* __restrict__ b4,
                                              float* __restrict__ out) {
    __shared__ float t3[324];
    __shared__ float part[64][8];
    int n = blockIdx.x, t = threadIdx.x;
    for (int i = t; i < 324; i += 128) t3[i] = tanhf(C3f[n * 324 + i] + b3[i]);
    __syncthreads();
    if (t < 64) {
        float acc[8];
#pragma unroll
        for (int j = 0; j < 8; ++j) acc[j] = 0.f;
#pragma unroll
        for (int kk = 0; kk < 6; ++kk) {
            int k = t + 64 * kk;
            if (k < 324) {
                float v = t3[k];
                f32x4 w0 = *(const f32x4*)(W4 + k * 8);
                f32x4 w1 = *(const f32x4*)(W4 + k * 8 + 4);
                acc[0] += v * w0[0]; acc[1] += v * w0[1];
                acc[2] += v * w0[2]; acc[3] += v * w0[3];
                acc[4] += v * w1[0]; acc[5] += v * w1[1];
                acc[6] += v * w1[2]; acc[7] += v * w1[3];
            }
        }
#pragma unroll
        for (int j = 0; j < 8; ++j) part[t][j] = acc[j];
    }
    __syncthreads();
    if (t < 8) {
        float acc = b4[t];
        for (int l = 0; l < 64; ++l) acc += part[l][t];
        out[n * 9 + t] = acc;
    } else if (t == 8) {
        out[n * 9 + 8] = 1.0f;
    }
}

// ---------------------------------------------------------------------------
// Workspace layout (bytes). All activations K-packed: [f>>5][batch64][f&31].
//   Abuf @ 0        2654208  bf16 648 blk x 64 x 32
//   C1f  @ 2654208  1327104  f32  162 blk            \
//   C2f  @ 3981312   335872  f32   41 blk (1296 pad)  } one memset (1745920 B)
//   C3f  @ 4317184    82944  f32  [64][324] linear   /
// ---------------------------------------------------------------------------
extern "C" void kernel_launch(void* const* d_in, const int* in_sizes, int n_in,
                              void* d_out, int out_size, void* d_ws, size_t ws_size,
                              hipStream_t stream) {
    const float* x1 = (const float*)d_in[0];
    const float* x2 = (const float*)d_in[1];
    const float* w1 = (const float*)d_in[2];
    const float* b1 = (const float*)d_in[3];
    const float* w2 = (const float*)d_in[4];
    const float* b2 = (const float*)d_in[5];
    const float* w3 = (const float*)d_in[6];
    const float* b3 = (const float*)d_in[7];
    const float* w4 = (const float*)d_in[8];
    const float* b4 = (const float*)d_in[9];
    float* out = (float*)d_out;

    char* ws = (char*)d_ws;
    unsigned short* Abuf = (unsigned short*)(ws + 0);
    float* C1f = (float*)(ws + 2654208);
    float* C2f = (float*)(ws + 3981312);
    float* C3f = (float*)(ws + 4317184);

    hipMemsetAsync(ws + 2654208, 0, 1745920, stream);   // zero C1f..C3f
    kcorr2<<<192, 1024, 0, stream>>>(x1, x2, Abuf);
    kgemm<5184, 20736, 1152><<<dim3(81, 18), 256, 0, stream>>>(Abuf, w1, C1f);
    kgemm2f<1296, 5184, 192><<<dim3(21, 27), 256, 0, stream>>>(C1f, b1, w2, C2f);
    kgemm3<<<dim3(64, 8), 384, 0, stream>>>(C2f, b2, w3, C3f);
    kep3g4<<<64, 128, 0, stream>>>(C3f, b3, w4, b4, out);
}